// Round 4
// baseline (528.436 us; speedup 1.0000x reference)
//
#include <hip/hip_runtime.h>
#include <hip/hip_bf16.h>
#include <stdint.h>

#define HP 58
#define WP 64
#define CIN 256
#define COUT 256
#define HH 56
#define WW 56
#define IMG_STRIDE (HP*WP*CIN)   // bytes per image in xb (i8): 950272
#define ROW_STRIDE (WP*CIN)      // bytes per padded row in xb: 16384
#define NPIX 200704.0            // 64*56*56

typedef __attribute__((ext_vector_type(4))) int i32x4;

#define GLDS(g, l) __builtin_amdgcn_global_load_lds( \
    (const __attribute__((address_space(1))) void*)(g), \
    (__attribute__((address_space(3))) void*)(l), 16, 0, 0)

// ---------- K1: per-(channel,image) partial sums in fp64 (deterministic) ----------
__global__ __launch_bounds__(256) void stats_partial(const float* __restrict__ x,
                                                     double* __restrict__ part) {
  int b = blockIdx.x;            // 256*64
  int c = b >> 6, n = b & 63;
  const float4* p = (const float4*)(x + (size_t)(n*CIN + c) * (HH*WW));
  double s = 0.0, s2 = 0.0;
  for (int i = threadIdx.x; i < 784; i += 256) {   // 784 float4 = 3136 floats
    float4 v = p[i];
    double a0 = v.x, a1 = v.y, a2 = v.z, a3 = v.w;
    s  += (a0 + a1) + (a2 + a3);
    s2 += (a0*a0 + a1*a1) + (a2*a2 + a3*a3);
  }
  for (int off = 32; off > 0; off >>= 1) {
    s  += __shfl_down(s, off);
    s2 += __shfl_down(s2, off);
  }
  __shared__ double red[8];
  int wv = threadIdx.x >> 6, ln = threadIdx.x & 63;
  if (ln == 0) { red[wv*2] = s; red[wv*2+1] = s2; }
  __syncthreads();
  if (threadIdx.x == 0) {
    double ts = ((red[0]+red[2])+red[4])+red[6];
    double t2 = ((red[1]+red[3])+red[5])+red[7];
    part[(size_t)(c*64 + n)*2]     = ts;
    part[(size_t)(c*64 + n)*2 + 1] = t2;
  }
}

// ---------- K2: finalize per-channel {mean, gamma*inv_std, beta} in fp64 ----------
__global__ void stats_final(const double* __restrict__ part,
                            const float* __restrict__ gamma,
                            const float* __restrict__ beta,
                            double* __restrict__ prm) {
  int c = threadIdx.x;
  double s = 0.0, s2 = 0.0;
  for (int n = 0; n < 64; ++n) {
    s  += part[(size_t)(c*64+n)*2];
    s2 += part[(size_t)(c*64+n)*2 + 1];
  }
  double mean = s / NPIX;
  double var  = s2 / NPIX - mean*mean;
  double inv  = 1.0 / sqrt(var + 1e-5);
  prm[c*4+0] = mean;
  prm[c*4+1] = (double)gamma[c] * inv;
  prm[c*4+2] = (double)beta[c];
}

// ---------- K3: binarize + transpose to padded NHWC64 int8 (float4 reads) ----------
__global__ __launch_bounds__(256) void binarize(const float* __restrict__ x,
                                                const double* __restrict__ prm,
                                                int8_t* __restrict__ xb) {
  int b = blockIdx.x;            // 64*58
  int n = b / HP, y = b % HP;
  int8_t* orow = xb + (size_t)(n*HP + y) * ROW_STRIDE;
  if (y == 0 || y == HP-1) {     // zero padding rows: 16384 B
    int4 z = {0,0,0,0};
    int4* q = (int4*)orow;
    for (int i = threadIdx.x; i < ROW_STRIDE/16; i += 256) q[i] = z;
    return;
  }
  __shared__ char sbuf[WW][260];   // 260 = 65 dwords (odd) -> conflict-free write-phase reads
  int h  = y - 1;
  int tid = threadIdx.x;
  #pragma unroll
  for (int it = 0; it < 14; ++it) {        // 14*256 = 3584 = 256c * 14 float4
    int t = it*256 + tid;
    int c = t / 14, j = t - c*14;
    float4 v = *(const float4*)(x + (size_t)(n*CIN + c)*(HH*WW) + h*WW + j*4);
    double mu = prm[c*4], gi = prm[c*4+1], be = prm[c*4+2];
    #pragma unroll
    for (int e = 0; e < 4; ++e) {
      double xv = (double)((&v.x)[e]);
      double vv = (xv - mu)*gi + be;
      sbuf[j*4+e][c] = vv > 0.0 ? (int8_t)1 : (vv < 0.0 ? (int8_t)-1 : (int8_t)0);
    }
  }
  __syncthreads();
  // write phase: 4 padded cols per iter, uint32 (4 channels) per thread, coalesced
  int xh = tid >> 6, cq = tid & 63;
  uint32_t* orow32 = (uint32_t*)orow;
  for (int xx0 = 0; xx0 < WP; xx0 += 4) {
    int xx = xx0 + xh;
    uint32_t v = 0;
    if (xx >= 1 && xx <= WW) v = *(const uint32_t*)&sbuf[xx-1][cq*4];
    orow32[xx*64 + cq] = v;
  }
}

// ---------- K4: quantize W[co][ci][3][3] fp32 -> Wb[tap][co][ci] i8, per-co scale ----------
__global__ __launch_bounds__(256) void wrepack(const float* __restrict__ W,
                                               int8_t* __restrict__ Wb,
                                               float* __restrict__ invs) {
  int co = blockIdx.x, ci = threadIdx.x;
  float w[9]; float mx = 0.f;
  const float* p = W + (size_t)co*(CIN*9) + ci*9;
  #pragma unroll
  for (int t = 0; t < 9; ++t) { w[t] = p[t]; mx = fmaxf(mx, fabsf(w[t])); }
  for (int off = 32; off > 0; off >>= 1) mx = fmaxf(mx, __shfl_xor(mx, off));
  __shared__ float sm[4];
  if ((threadIdx.x & 63) == 0) sm[threadIdx.x >> 6] = mx;
  __syncthreads();
  mx = fmaxf(fmaxf(sm[0], sm[1]), fmaxf(sm[2], sm[3]));
  float s = mx > 0.f ? 127.f / mx : 0.f;
  #pragma unroll
  for (int t = 0; t < 9; ++t) {
    int q = (int)lrintf(w[t] * s);
    q = q > 127 ? 127 : (q < -127 ? -127 : q);
    Wb[t*(COUT*CIN) + co*CIN + ci] = (int8_t)q;
  }
  if (threadIdx.x == 0) invs[co] = mx / 127.f;
}

// ---------- K5: implicit-GEMM conv, int8: A direct global->VGPR (L1-served), B 4-buf LDS ----------
// D[co][pos] = sum Wb[tap][co][ci]*X[pos][ci], 18 K-steps of 128 ci.
// LDS = 4 x 32KB round-robin B buffers (256 pos x 128 B, XOR-swizzled (row&7)<<4).
// Per step, per wave: 16 global dwordx4 (A), 4 global_load_lds (B(s+2)), 8 ds_read_b128 (B(s)),
// s_waitcnt vmcnt(4) lgkmcnt(0), ONE s_barrier, 64 MFMA.
__global__ __launch_bounds__(512, 2) void conv_gemm(const int8_t* __restrict__ xb,
                                                    const int8_t* __restrict__ Wb,
                                                    const float* __restrict__ invs,
                                                    float* __restrict__ out) {
  extern __shared__ char smem[];
  int bid = blockIdx.x;
  int swz = (bid & 7) * 112 + (bid >> 3);    // XCD-aware, bijective (896 % 8 == 0)
  int n_img = swz / 14, rg = swz - n_img * 14;
  int y0 = 1 + rg * 4;                       // 4 padded rows y0..y0+3

  int tid = threadIdx.x;
  int ln = tid & 63, wid = tid >> 6;
  int wm = wid >> 2, wn = wid & 3;

  int srowT = tid >> 3;                        // 0..63
  int scolB = ((tid & 7) ^ (srowT & 7)) * 16;  // pre-swizzled source col (bytes)

  size_t xoff = (size_t)n_img * IMG_STRIDE + (size_t)(y0 - 1) * ROW_STRIDE;

  auto STAGE_B = [&](int step) {               // one 32KB B tile (256 pos rows)
    int sc = step < 18 ? step : 17;            // tail: clamp SOURCE only
    int tap = sc >> 1, ci0 = (sc & 1) << 7;
    int kh = tap / 3, kw = tap - kh*3;
    const int8_t* src = xb + xoff + (long)kh * ROW_STRIDE + (long)(kw - 1) * CIN + ci0
                           + (size_t)srowT * CIN + scolB;
    char* dst = smem + ((step & 3) << 15) + tid * 16;
    GLDS(src,             dst);
    GLDS(src +  64*CIN,   dst + 8192);
    GLDS(src + 128*CIN,   dst + 16384);
    GLDS(src + 192*CIN,   dst + 24576);
  };

  i32x4 acc[8][4] = {};

  STAGE_B(0); STAGE_B(1);
  asm volatile("s_waitcnt vmcnt(4)" ::: "memory");   // B(0) complete
  __builtin_amdgcn_s_barrier();

  // A-frag: row = wm*128 + m*16 + (ln&15), kchunk = ln>>4 (16B), kk -> +64
  const int8_t* abase = Wb + (size_t)(wm*128 + (ln & 15)) * CIN + ((ln >> 4) << 4);
  // B-frag: row = wn*64 + nn*16 + (ln&15); byte = row*128 + kpart^((row&7)<<4)
  int brow = wn*64 + (ln & 15);
  int ksw  = ((ln >> 4) << 4) ^ ((brow & 7) << 4);   // nn*16 keeps row&7 invariant

  #pragma unroll 1
  for (int s = 0; s < 18; ++s) {
    int tap = s >> 1, ci0 = (s & 1) << 7;
    const int8_t* ab = abase + (size_t)tap * (COUT*CIN) + ci0;
    i32x4 a[8][2], b[4][2];
    #pragma unroll
    for (int m = 0; m < 8; ++m) {
      a[m][0] = *(const i32x4*)(ab + m*16*CIN);
      a[m][1] = *(const i32x4*)(ab + m*16*CIN + 64);
    }
    STAGE_B(s + 2);
    const char* Bb = smem + ((s & 3) << 15);
    #pragma unroll
    for (int nn = 0; nn < 4; ++nn) {
      const char* rb = Bb + (brow + nn*16) * 128;
      b[nn][0] = *(const i32x4*)(rb + ksw);
      b[nn][1] = *(const i32x4*)(rb + (ksw ^ 64));
    }
    // per-wave drain: everything except the 4 newest (GLDS B(s+2)); then block sync
    asm volatile("s_waitcnt vmcnt(4) lgkmcnt(0)" ::: "memory");
    __builtin_amdgcn_s_barrier();
    __builtin_amdgcn_s_setprio(1);
    #pragma unroll
    for (int m = 0; m < 8; ++m)
      #pragma unroll
      for (int nn = 0; nn < 4; ++nn) {
        acc[m][nn] = __builtin_amdgcn_mfma_i32_16x16x64_i8(a[m][0], b[nn][0], acc[m][nn], 0, 0, 0);
        acc[m][nn] = __builtin_amdgcn_mfma_i32_16x16x64_i8(a[m][1], b[nn][1], acc[m][nn], 0, 0, 0);
      }
    __builtin_amdgcn_s_setprio(0);
  }

  // ---------------- epilogue: per-wave 64x64 LDS transpose -> coalesced dwordx4 stores ----
  asm volatile("s_waitcnt vmcnt(0)" ::: "memory");   // tail GLDS must not race LDS reuse
  __syncthreads();

  float ivv[8][4];
  #pragma unroll
  for (int m = 0; m < 8; ++m)
    #pragma unroll
    for (int r = 0; r < 4; ++r)
      ivv[m][r] = invs[wm*128 + m*16 + (ln >> 4)*4 + r];

  char* eb = smem + wid * 16384;               // 64 rows x 256B, swizzle ((row&7)<<5)
  int y = y0 + wn;
  size_t obase = (size_t)n_img * COUT * (HH*WW) + (size_t)(y - 1) * WW;

  #pragma unroll
  for (int p = 0; p < 2; ++p) {
    #pragma unroll
    for (int m2 = 0; m2 < 4; ++m2) {
      int m = p*4 + m2;
      #pragma unroll
      for (int nn = 0; nn < 4; ++nn)
        #pragma unroll
        for (int r = 0; r < 4; ++r) {
          int row  = m2*16 + (ln >> 4)*4 + r;
          int slot = (nn*16 + (ln & 15) + 63) & 63;   // xx -> x=xx-1 (xx=0 parks at 63)
          float v = fmaxf((float)acc[m][nn][r] * ivv[m][r], 0.0f);
          *(float*)(eb + row*256 + ((slot*4) ^ ((row & 7) << 5))) = v;
        }
    }
    asm volatile("s_waitcnt lgkmcnt(0)" ::: "memory");
    int co = wm*128 + p*64 + ln;
    const char* rbase = eb + ln*256;
    float* op = out + obase + (size_t)co * (HH*WW);
    #pragma unroll
    for (int j = 0; j < 14; ++j) {           // x = 4j..4j+3, 16B-aligned rows of 224B
      float4 v = *(const float4*)(rbase + ((j*16) ^ ((ln & 7) << 5)));
      *(float4*)(op + j*4) = v;
    }
    asm volatile("s_waitcnt lgkmcnt(0)" ::: "memory");  // reads done before p=1 overwrites
  }
}

extern "C" void kernel_launch(void* const* d_in, const int* in_sizes, int n_in,
                              void* d_out, int out_size, void* d_ws, size_t ws_size,
                              hipStream_t stream) {
  const float* x     = (const float*)d_in[0];
  const float* gamma = (const float*)d_in[1];
  const float* beta  = (const float*)d_in[2];
  const float* W     = (const float*)d_in[3];
  float* out = (float*)d_out;

  char* ws = (char*)d_ws;
  // layout: part [262144] | prm [8192] | invs [1024] | Wb i8 [589824] | pad | xb i8 @1MiB
  double*  part = (double*)ws;
  double*  prm  = (double*)(ws + 262144);
  float*   invs = (float*)(ws + 270336);
  int8_t*  Wb   = (int8_t*)(ws + 271360);
  int8_t*  xbuf = (int8_t*)(ws + 1048576);
  // xb: 64*58*64*256 = 60,817,408 B (+~512B tap-overhang read slack within ws)

  (void)hipFuncSetAttribute((const void*)conv_gemm,
                            hipFuncAttributeMaxDynamicSharedMemorySize, 131072);

  hipLaunchKernelGGL(wrepack,       dim3(256),    dim3(256), 0, stream, W, Wb, invs);
  hipLaunchKernelGGL(stats_partial, dim3(256*64), dim3(256), 0, stream, x, part);
  hipLaunchKernelGGL(stats_final,   dim3(1),      dim3(256), 0, stream, part, gamma, beta, prm);
  hipLaunchKernelGGL(binarize,      dim3(64*HP),  dim3(256), 0, stream, x, prm, xbuf);
  hipLaunchKernelGGL(conv_gemm,     dim3(896),    dim3(512), 131072, stream, xbuf, Wb, invs, out);
}

// Round 6
// 321.167 us; speedup vs baseline: 1.6454x; 1.6454x over previous
//
#include <hip/hip_runtime.h>
#include <hip/hip_bf16.h>
#include <stdint.h>

#define HP 58
#define WP 64
#define CIN 256
#define COUT 256
#define HH 56
#define WW 56
#define IMG_STRIDE (HP*WP*CIN)   // bytes per image in xb (i8): 950272
#define ROW_STRIDE (WP*CIN)      // bytes per padded row in xb: 16384
#define NPIX 200704.0            // 64*56*56

// conv LDS layout (dynamic, 142336 B):
//   [0,2048)        guard (x_in = -1 reads land here)
//   [2048,91136)    X: 6 rows x 58 cols x 256B (row stride 14848), col-swizzled
//   [91136,93184)   guard (x_in up to 64 + tail reads)
//   [93184,142336)  A ring: 3 x 16384 (k-slice-major: slice*4096 + row*16)
#define XO    2048
#define XROW  14848
#define AO    93184
#define LDS_TOTAL 142336

typedef __attribute__((ext_vector_type(4))) int i32x4;

#define GLDS(g, l) __builtin_amdgcn_global_load_lds( \
    (const __attribute__((address_space(1))) void*)(g), \
    (__attribute__((address_space(3))) void*)(l), 16, 0, 0)

// ---------- K1: per-(channel,image) partial sums in fp64 (deterministic) ----------
__global__ __launch_bounds__(256) void stats_partial(const float* __restrict__ x,
                                                     double* __restrict__ part) {
  int b = blockIdx.x;            // 256*64
  int c = b >> 6, n = b & 63;
  const float4* p = (const float4*)(x + (size_t)(n*CIN + c) * (HH*WW));
  double s = 0.0, s2 = 0.0;
  for (int i = threadIdx.x; i < 784; i += 256) {
    float4 v = p[i];
    double a0 = v.x, a1 = v.y, a2 = v.z, a3 = v.w;
    s  += (a0 + a1) + (a2 + a3);
    s2 += (a0*a0 + a1*a1) + (a2*a2 + a3*a3);
  }
  for (int off = 32; off > 0; off >>= 1) {
    s  += __shfl_down(s, off);
    s2 += __shfl_down(s2, off);
  }
  __shared__ double red[8];
  int wv = threadIdx.x >> 6, ln = threadIdx.x & 63;
  if (ln == 0) { red[wv*2] = s; red[wv*2+1] = s2; }
  __syncthreads();
  if (threadIdx.x == 0) {
    double ts = ((red[0]+red[2])+red[4])+red[6];
    double t2 = ((red[1]+red[3])+red[5])+red[7];
    part[(size_t)(c*64 + n)*2]     = ts;
    part[(size_t)(c*64 + n)*2 + 1] = t2;
  }
}

// ---------- K2: finalize per-channel {mean, gamma*inv_std, beta} in fp64 ----------
__global__ void stats_final(const double* __restrict__ part,
                            const float* __restrict__ gamma,
                            const float* __restrict__ beta,
                            double* __restrict__ prm) {
  int c = threadIdx.x;
  double s = 0.0, s2 = 0.0;
  for (int n = 0; n < 64; ++n) {
    s  += part[(size_t)(c*64+n)*2];
    s2 += part[(size_t)(c*64+n)*2 + 1];
  }
  double mean = s / NPIX;
  double var  = s2 / NPIX - mean*mean;
  double inv  = 1.0 / sqrt(var + 1e-5);
  prm[c*4+0] = mean;
  prm[c*4+1] = (double)gamma[c] * inv;
  prm[c*4+2] = (double)beta[c];
}

// ---------- K3: binarize + transpose to padded NHWC64 int8 (float4 reads) ----------
__global__ __launch_bounds__(256) void binarize(const float* __restrict__ x,
                                                const double* __restrict__ prm,
                                                int8_t* __restrict__ xb) {
  int b = blockIdx.x;            // 64*58
  int n = b / HP, y = b % HP;
  int8_t* orow = xb + (size_t)(n*HP + y) * ROW_STRIDE;
  if (y == 0 || y == HP-1) {     // zero padding rows: 16384 B
    int4 z = {0,0,0,0};
    int4* q = (int4*)orow;
    for (int i = threadIdx.x; i < ROW_STRIDE/16; i += 256) q[i] = z;
    return;
  }
  __shared__ char sbuf[WW][260];   // odd dword stride -> conflict-free
  int h  = y - 1;
  int tid = threadIdx.x;
  #pragma unroll
  for (int it = 0; it < 14; ++it) {        // 14*256 = 3584 = 256c * 14 float4
    int t = it*256 + tid;
    int c = t / 14, j = t - c*14;
    float4 v = *(const float4*)(x + (size_t)(n*CIN + c)*(HH*WW) + h*WW + j*4);
    double mu = prm[c*4], gi = prm[c*4+1], be = prm[c*4+2];
    #pragma unroll
    for (int e = 0; e < 4; ++e) {
      double xv = (double)((&v.x)[e]);
      double vv = (xv - mu)*gi + be;
      sbuf[j*4+e][c] = vv > 0.0 ? (int8_t)1 : (vv < 0.0 ? (int8_t)-1 : (int8_t)0);
    }
  }
  __syncthreads();
  int xh = tid >> 6, cq = tid & 63;
  uint32_t* orow32 = (uint32_t*)orow;
  for (int xx0 = 0; xx0 < WP; xx0 += 4) {
    int xx = xx0 + xh;
    uint32_t v = 0;
    if (xx >= 1 && xx <= WW) v = *(const uint32_t*)&sbuf[xx-1][cq*4];
    orow32[xx*64 + cq] = v;
  }
}

// ---------- K4: quantize W[co][ci][3][3] fp32 -> Wb[tap][co][ci] i8, per-co scale ----------
__global__ __launch_bounds__(256) void wrepack(const float* __restrict__ W,
                                               int8_t* __restrict__ Wb,
                                               float* __restrict__ invs) {
  int co = blockIdx.x, ci = threadIdx.x;
  float w[9]; float mx = 0.f;
  const float* p = W + (size_t)co*(CIN*9) + ci*9;
  #pragma unroll
  for (int t = 0; t < 9; ++t) { w[t] = p[t]; mx = fmaxf(mx, fabsf(w[t])); }
  for (int off = 32; off > 0; off >>= 1) mx = fmaxf(mx, __shfl_xor(mx, off));
  __shared__ float sm[4];
  if ((threadIdx.x & 63) == 0) sm[threadIdx.x >> 6] = mx;
  __syncthreads();
  mx = fmaxf(fmaxf(sm[0], sm[1]), fmaxf(sm[2], sm[3]));
  float s = mx > 0.f ? 127.f / mx : 0.f;
  #pragma unroll
  for (int t = 0; t < 9; ++t) {
    int q = (int)lrintf(w[t] * s);
    q = q > 127 ? 127 : (q < -127 ? -127 : q);
    Wb[t*(COUT*CIN) + co*CIN + ci] = (int8_t)q;
  }
  if (threadIdx.x == 0) invs[co] = mx / 127.f;
}

// ---------- K5: implicit-GEMM conv, int8. X staged ONCE (resident); A 3-ring K64 ----------
// Per step s (36 = 9 taps x 4 ci-quarters): vmcnt(2); s_barrier; STAGE_A(s+2);
// 12 ds_read_b128 (A 8, B 4 from resident X at tap shift); lgkmcnt(0)+sched_barrier;
// 32 mfma_i32_16x16x64_i8.
__global__ __launch_bounds__(512, 2) void conv_gemm(const int8_t* __restrict__ xb,
                                                    const int8_t* __restrict__ Wb,
                                                    const float* __restrict__ invs,
                                                    float* __restrict__ out) {
  extern __shared__ char smem[];
  int bid = blockIdx.x;
  int swz = (bid & 7) * 112 + (bid >> 3);    // XCD-aware, bijective (896 % 8 == 0)
  int n_img = swz / 14, rg = swz - n_img * 14;
  int y0 = 1 + rg * 4;                       // output rows y0..y0+3 (padded coords)

  int tid = threadIdx.x;
  int ln = tid & 63, wid = tid >> 6;
  int wm = wid >> 2, wn = wid & 3;           // wm: co half, wn: y-row

  size_t xoff = (size_t)n_img * IMG_STRIDE + (size_t)(y0 - 1) * ROW_STRIDE;

  // ---- prologue: stage X once: 6 rows x 58 cols x 256 B, pre-swizzled source ----
  #pragma unroll
  for (int i = 0; i < 11; ++i) {
    int o = tid*16 + i*8192;
    if (o < 89088) {                          // wave-uniform divergence only (89088 = 87*1024)
      int r   = o / XROW;
      int rem = o - r*XROW;
      int xx  = rem >> 8, cb = rem & 255;
      const int8_t* src = xb + xoff + r*ROW_STRIDE + xx*256 + (cb ^ ((xx & 7) << 4));
      GLDS(src, smem + XO + o);
    }
  }

  // ---- A staging: chunk = slice(4)x[row(256)x16B]; 2 GLDS/thread ----
  int arow = tid & 255, aslice = tid >> 8;
  auto STAGE_A = [&](int s, int buf) {
    int sc = s < 36 ? s : 35;                 // tail clamp (source only)
    int tap = sc >> 2, ci0 = (sc & 3) << 6;
    const int8_t* base = Wb + tap*(COUT*CIN) + arow*256 + ci0;
    char* dst = smem + AO + buf*16384 + tid*16;
    GLDS(base + aslice*16,       dst);
    GLDS(base + (2+aslice)*16,   dst + 8192);
  };

  i32x4 acc[8][4] = {};
  STAGE_A(0, 0); STAGE_A(1, 1);

  // A-frag: byte = kslice*4096 + (wm*128 + m*16 + (ln&15))*16   [FIX: wm term restored]
  int afrag = ((ln >> 4) << 12) + (wm*128 + (ln & 15)) * 16;
  int xx0   = ln & 15;                        // + nn*16 + kw - 1
  int cb16  = (ln >> 4) << 4;
  int bufr = 0, bufs = 2;

  #pragma unroll 1
  for (int s = 0; s < 36; ++s) {
    asm volatile("s_waitcnt vmcnt(2)" ::: "memory");   // A(s) landed (mine); barrier -> all
    __builtin_amdgcn_s_barrier();
    STAGE_A(s + 2, bufs);

    int tap = s >> 2, ci0q = (s & 3) << 6;
    int kh = (tap * 11) >> 5;                 // floor(tap/3) for 0..8
    int kw = tap - kh * 3;

    i32x4 a[8], b[4];
    const char* Ab = smem + AO + bufr*16384 + afrag;
    #pragma unroll
    for (int m = 0; m < 8; ++m) a[m] = *(const i32x4*)(Ab + m*256);
    int cb = ci0q + cb16;
    const char* Xr = smem + XO + (wn + kh) * XROW;
    #pragma unroll
    for (int nn = 0; nn < 4; ++nn) {
      int x_in = xx0 + nn*16 + kw - 1;
      b[nn] = *(const i32x4*)(Xr + x_in*256 + (cb ^ ((x_in & 7) << 4)));
    }

    asm volatile("s_waitcnt lgkmcnt(0)" ::: "memory");
    __builtin_amdgcn_sched_barrier(0);
    __builtin_amdgcn_s_setprio(1);
    #pragma unroll
    for (int m = 0; m < 8; ++m)
      #pragma unroll
      for (int nn = 0; nn < 4; ++nn)
        acc[m][nn] = __builtin_amdgcn_mfma_i32_16x16x64_i8(a[m], b[nn], acc[m][nn], 0, 0, 0);
    __builtin_amdgcn_s_setprio(0);

    bufr = bufr == 2 ? 0 : bufr + 1;
    bufs = bufs == 2 ? 0 : bufs + 1;
  }

  // ---------------- epilogue: per-wave 64x64 LDS transpose -> coalesced dwordx4 ----
  asm volatile("s_waitcnt vmcnt(0)" ::: "memory");     // tail A stages before LDS reuse
  __syncthreads();

  float ivv[8][4];
  #pragma unroll
  for (int m = 0; m < 8; ++m)
    #pragma unroll
    for (int r = 0; r < 4; ++r)
      ivv[m][r] = invs[wm*128 + m*16 + (ln >> 4)*4 + r];

  char* eb = smem + wid * 16384;               // 64 rows x 256B, swizzle ((row&7)<<5)
  int y = y0 + wn;
  size_t obase = (size_t)n_img * COUT * (HH*WW) + (size_t)(y - 1) * WW;

  #pragma unroll
  for (int p = 0; p < 2; ++p) {
    #pragma unroll
    for (int m2 = 0; m2 < 4; ++m2) {
      int m = p*4 + m2;
      #pragma unroll
      for (int nn = 0; nn < 4; ++nn)
        #pragma unroll
        for (int r = 0; r < 4; ++r) {
          int row  = m2*16 + (ln >> 4)*4 + r;
          int slot = (nn*16 + (ln & 15) + 63) & 63;   // xx -> x=xx-1 (xx=0 parks at 63)
          float v = fmaxf((float)acc[m][nn][r] * ivv[m][r], 0.0f);
          *(float*)(eb + row*256 + ((slot*4) ^ ((row & 7) << 5))) = v;
        }
    }
    asm volatile("s_waitcnt lgkmcnt(0)" ::: "memory");
    __builtin_amdgcn_s_barrier();
    int co = wm*128 + p*64 + ln;
    const char* rbase = eb + ln*256;
    float* op = out + obase + (size_t)co * (HH*WW);
    #pragma unroll
    for (int j = 0; j < 14; ++j) {             // x = 4j..4j+3
      float4 v = *(const float4*)(rbase + ((j*16) ^ ((ln & 7) << 5)));
      *(float4*)(op + j*4) = v;
    }
    asm volatile("s_waitcnt lgkmcnt(0)" ::: "memory");
    __builtin_amdgcn_s_barrier();
  }
}

extern "C" void kernel_launch(void* const* d_in, const int* in_sizes, int n_in,
                              void* d_out, int out_size, void* d_ws, size_t ws_size,
                              hipStream_t stream) {
  const float* x     = (const float*)d_in[0];
  const float* gamma = (const float*)d_in[1];
  const float* beta  = (const float*)d_in[2];
  const float* W     = (const float*)d_in[3];
  float* out = (float*)d_out;

  char* ws = (char*)d_ws;
  // layout: part [262144] | prm [8192] | invs [1024] | Wb i8 [589824] | pad | xb i8 @1MiB
  double*  part = (double*)ws;
  double*  prm  = (double*)(ws + 262144);
  float*   invs = (float*)(ws + 270336);
  int8_t*  Wb   = (int8_t*)(ws + 271360);
  int8_t*  xbuf = (int8_t*)(ws + 1048576);
  // xb: 64*58*64*256 = 60,817,408 B

  (void)hipFuncSetAttribute((const void*)conv_gemm,
                            hipFuncAttributeMaxDynamicSharedMemorySize, LDS_TOTAL);

  hipLaunchKernelGGL(wrepack,       dim3(256),    dim3(256), 0, stream, W, Wb, invs);
  hipLaunchKernelGGL(stats_partial, dim3(256*64), dim3(256), 0, stream, x, part);
  hipLaunchKernelGGL(stats_final,   dim3(1),      dim3(256), 0, stream, part, gamma, beta, prm);
  hipLaunchKernelGGL(binarize,      dim3(64*HP),  dim3(256), 0, stream, x, prm, xbuf);
  hipLaunchKernelGGL(conv_gemm,     dim3(896),    dim3(512), LDS_TOTAL, stream, xbuf, Wb, invs, out);
}

// Round 7
// 281.859 us; speedup vs baseline: 1.8748x; 1.1395x over previous
//
#include <hip/hip_runtime.h>
#include <hip/hip_bf16.h>
#include <stdint.h>

#define HP 58
#define WP 64
#define CIN 256
#define COUT 256
#define HH 56
#define WW 56
#define IMG_STRIDE (HP*WP*CIN)   // bytes per image in xb (i8): 950272
#define ROW_STRIDE (WP*CIN)      // bytes per padded row in xb: 16384
#define NPIX 200704.0            // 64*56*56

// conv LDS layout (dynamic, 158720 B):
//   [0,2048)        guard (x_in = -1 reads land here)
//   [2048,91136)    X: 6 rows x 58 cols x 256B (row stride 14848), col-swizzled
//   [91136,93184)   guard (x_in up to 64 + tail reads)
//   [93184,158720)  A ring: 4 x 16384 (k-slice-major: slice*4096 + row*16)
#define XO    2048
#define XROW  14848
#define AO    93184
#define LDS_TOTAL 158720

typedef __attribute__((ext_vector_type(4))) int i32x4;

#define GLDS(g, l) __builtin_amdgcn_global_load_lds( \
    (const __attribute__((address_space(1))) void*)(g), \
    (__attribute__((address_space(3))) void*)(l), 16, 0, 0)

// ---------- K1: per-(channel,image) partial sums in fp64 (deterministic) ----------
__global__ __launch_bounds__(256) void stats_partial(const float* __restrict__ x,
                                                     double* __restrict__ part) {
  int b = blockIdx.x;            // 256*64
  int c = b >> 6, n = b & 63;
  const float4* p = (const float4*)(x + (size_t)(n*CIN + c) * (HH*WW));
  double s = 0.0, s2 = 0.0;
  for (int i = threadIdx.x; i < 784; i += 256) {
    float4 v = p[i];
    double a0 = v.x, a1 = v.y, a2 = v.z, a3 = v.w;
    s  += (a0 + a1) + (a2 + a3);
    s2 += (a0*a0 + a1*a1) + (a2*a2 + a3*a3);
  }
  for (int off = 32; off > 0; off >>= 1) {
    s  += __shfl_down(s, off);
    s2 += __shfl_down(s2, off);
  }
  __shared__ double red[8];
  int wv = threadIdx.x >> 6, ln = threadIdx.x & 63;
  if (ln == 0) { red[wv*2] = s; red[wv*2+1] = s2; }
  __syncthreads();
  if (threadIdx.x == 0) {
    double ts = ((red[0]+red[2])+red[4])+red[6];
    double t2 = ((red[1]+red[3])+red[5])+red[7];
    part[(size_t)(c*64 + n)*2]     = ts;
    part[(size_t)(c*64 + n)*2 + 1] = t2;
  }
}

// ---------- K2: finalize per-channel {mean, gamma*inv_std, beta} in fp64 ----------
__global__ void stats_final(const double* __restrict__ part,
                            const float* __restrict__ gamma,
                            const float* __restrict__ beta,
                            double* __restrict__ prm) {
  int c = threadIdx.x;
  double s = 0.0, s2 = 0.0;
  for (int n = 0; n < 64; ++n) {
    s  += part[(size_t)(c*64+n)*2];
    s2 += part[(size_t)(c*64+n)*2 + 1];
  }
  double mean = s / NPIX;
  double var  = s2 / NPIX - mean*mean;
  double inv  = 1.0 / sqrt(var + 1e-5);
  prm[c*4+0] = mean;
  prm[c*4+1] = (double)gamma[c] * inv;
  prm[c*4+2] = (double)beta[c];
}

// ---------- K3: binarize + transpose to padded NHWC64 int8 (float4 reads) ----------
__global__ __launch_bounds__(256) void binarize(const float* __restrict__ x,
                                                const double* __restrict__ prm,
                                                int8_t* __restrict__ xb) {
  int b = blockIdx.x;            // 64*58
  int n = b / HP, y = b % HP;
  int8_t* orow = xb + (size_t)(n*HP + y) * ROW_STRIDE;
  if (y == 0 || y == HP-1) {     // zero padding rows: 16384 B
    int4 z = {0,0,0,0};
    int4* q = (int4*)orow;
    for (int i = threadIdx.x; i < ROW_STRIDE/16; i += 256) q[i] = z;
    return;
  }
  __shared__ char sbuf[WW][260];   // odd dword stride -> conflict-free
  int h  = y - 1;
  int tid = threadIdx.x;
  #pragma unroll
  for (int it = 0; it < 14; ++it) {        // 14*256 = 3584 = 256c * 14 float4
    int t = it*256 + tid;
    int c = t / 14, j = t - c*14;
    float4 v = *(const float4*)(x + (size_t)(n*CIN + c)*(HH*WW) + h*WW + j*4);
    double mu = prm[c*4], gi = prm[c*4+1], be = prm[c*4+2];
    #pragma unroll
    for (int e = 0; e < 4; ++e) {
      double xv = (double)((&v.x)[e]);
      double vv = (xv - mu)*gi + be;
      sbuf[j*4+e][c] = vv > 0.0 ? (int8_t)1 : (vv < 0.0 ? (int8_t)-1 : (int8_t)0);
    }
  }
  __syncthreads();
  int xh = tid >> 6, cq = tid & 63;
  uint32_t* orow32 = (uint32_t*)orow;
  for (int xx0 = 0; xx0 < WP; xx0 += 4) {
    int xx = xx0 + xh;
    uint32_t v = 0;
    if (xx >= 1 && xx <= WW) v = *(const uint32_t*)&sbuf[xx-1][cq*4];
    orow32[xx*64 + cq] = v;
  }
}

// ---------- K4: quantize W[co][ci][3][3] fp32 -> Wb[tap][co][ci] i8, per-co scale ----------
__global__ __launch_bounds__(256) void wrepack(const float* __restrict__ W,
                                               int8_t* __restrict__ Wb,
                                               float* __restrict__ invs) {
  int co = blockIdx.x, ci = threadIdx.x;
  float w[9]; float mx = 0.f;
  const float* p = W + (size_t)co*(CIN*9) + ci*9;
  #pragma unroll
  for (int t = 0; t < 9; ++t) { w[t] = p[t]; mx = fmaxf(mx, fabsf(w[t])); }
  for (int off = 32; off > 0; off >>= 1) mx = fmaxf(mx, __shfl_xor(mx, off));
  __shared__ float sm[4];
  if ((threadIdx.x & 63) == 0) sm[threadIdx.x >> 6] = mx;
  __syncthreads();
  mx = fmaxf(fmaxf(sm[0], sm[1]), fmaxf(sm[2], sm[3]));
  float s = mx > 0.f ? 127.f / mx : 0.f;
  #pragma unroll
  for (int t = 0; t < 9; ++t) {
    int q = (int)lrintf(w[t] * s);
    q = q > 127 ? 127 : (q < -127 ? -127 : q);
    Wb[t*(COUT*CIN) + co*CIN + ci] = (int8_t)q;
  }
  if (threadIdx.x == 0) invs[co] = mx / 127.f;
}

// ---------- K5: implicit-GEMM conv, int8. X resident; A 4-ring; REGISTER-PIPELINED ----------
// body(s): vmcnt(2) [A(s+1) landed]; barrier; STAGE_A(s+3); issue 12 ds_reads for s+1 into
// NEXT reg set (no wait); MFMA on CUR set (compiler lgkmcnt(12) is already satisfied).
// Ring safety: buf (s+3)&3's previous readers finished >=2 barriers earlier; skew <1 step.
__global__ __launch_bounds__(512, 2) void conv_gemm(const int8_t* __restrict__ xb,
                                                    const int8_t* __restrict__ Wb,
                                                    const float* __restrict__ invs,
                                                    float* __restrict__ out) {
  extern __shared__ char smem[];
  int bid = blockIdx.x;
  int swz = (bid & 7) * 112 + (bid >> 3);    // XCD-aware, bijective (896 % 8 == 0)
  int n_img = swz / 14, rg = swz - n_img * 14;
  int y0 = 1 + rg * 4;                       // output rows y0..y0+3 (padded coords)

  int tid = threadIdx.x;
  int ln = tid & 63, wid = tid >> 6;
  int wm = wid >> 2, wn = wid & 3;           // wm: co half, wn: y-row

  size_t xoff = (size_t)n_img * IMG_STRIDE + (size_t)(y0 - 1) * ROW_STRIDE;

  // ---- prologue: stage X once: 6 rows x 58 cols x 256 B, pre-swizzled source ----
  #pragma unroll
  for (int i = 0; i < 11; ++i) {
    int o = tid*16 + i*8192;
    if (o < 89088) {                          // wave-uniform (89088 = multiple of 1024)
      int r   = o / XROW;
      int rem = o - r*XROW;
      int xx  = rem >> 8, cb = rem & 255;
      const int8_t* src = xb + xoff + r*ROW_STRIDE + xx*256 + (cb ^ ((xx & 7) << 4));
      GLDS(src, smem + XO + o);
    }
  }

  // ---- A staging: chunk = slice(4)x[row(256)x16B]; 2 GLDS/thread ----
  int arow = tid & 255, aslice = tid >> 8;
  auto STAGE_A = [&](int s, int buf) {
    int sc = s < 36 ? s : 35;                 // tail clamp (source only)
    int tap = sc >> 2, ci0 = (sc & 3) << 6;
    const int8_t* base = Wb + tap*(COUT*CIN) + arow*256 + ci0;
    char* dst = smem + AO + buf*16384 + tid*16;
    GLDS(base + aslice*16,       dst);
    GLDS(base + (2+aslice)*16,   dst + 8192);
  };

  i32x4 acc[8][4] = {};
  STAGE_A(0, 0); STAGE_A(1, 1); STAGE_A(2, 2);

  // A-frag: byte = kslice*4096 + (wm*128 + m*16 + (ln&15))*16
  int afrag = ((ln >> 4) << 12) + (wm*128 + (ln & 15)) * 16;
  int xx0   = ln & 15;
  int cb16  = (ln >> 4) << 4;

  i32x4 aR[2][8], bR[2][4];

  auto LOADF = [&](int s, i32x4 (&av)[8], i32x4 (&bv)[4]) {
    int sc = s < 36 ? s : 35;                 // geometry clamp; buf index unclamped
    const char* Ab = smem + AO + (s & 3)*16384 + afrag;
    #pragma unroll
    for (int m = 0; m < 8; ++m) av[m] = *(const i32x4*)(Ab + m*256);
    int tap = sc >> 2;
    int kh = (tap * 11) >> 5, kw = tap - kh * 3;
    int cb = ((sc & 3) << 6) + cb16;
    const char* Xr = smem + XO + (wn + kh) * XROW;
    #pragma unroll
    for (int nn = 0; nn < 4; ++nn) {
      int x_in = xx0 + nn*16 + kw - 1;
      bv[nn] = *(const i32x4*)(Xr + x_in*256 + (cb ^ ((x_in & 7) << 4)));
    }
  };

  // prologue wait: X + A(0) landed (per-wave), then block-sync; prefetch frags(0)
  asm volatile("s_waitcnt vmcnt(4)" ::: "memory");
  __builtin_amdgcn_s_barrier();
  LOADF(0, aR[0], bR[0]);

  auto body = [&](int s, i32x4 (&ac)[8], i32x4 (&bc)[4], i32x4 (&an)[8], i32x4 (&bn)[4]) {
    asm volatile("s_waitcnt vmcnt(2)" ::: "memory");   // A(s+1) landed (mine); barrier -> all
    __builtin_amdgcn_s_barrier();
    STAGE_A(s + 3, (s + 3) & 3);
    LOADF(s + 1, an, bn);                              // issue only; no drain
    __builtin_amdgcn_s_setprio(1);
    #pragma unroll
    for (int m = 0; m < 8; ++m)
      #pragma unroll
      for (int nn = 0; nn < 4; ++nn)
        acc[m][nn] = __builtin_amdgcn_mfma_i32_16x16x64_i8(ac[m], bc[nn], acc[m][nn], 0, 0, 0);
    __builtin_amdgcn_s_setprio(0);
  };

  #pragma unroll 1
  for (int t = 0; t < 18; ++t) {
    body(2*t,     aR[0], bR[0], aR[1], bR[1]);
    body(2*t + 1, aR[1], bR[1], aR[0], bR[0]);
  }

  // ---------------- epilogue: per-wave 64x64 transpose, conflict-free, coalesced ----
  asm volatile("s_waitcnt vmcnt(0)" ::: "memory");     // tail A stages before LDS reuse
  __syncthreads();

  float ivv[8][4];
  #pragma unroll
  for (int m = 0; m < 8; ++m)
    #pragma unroll
    for (int r = 0; r < 4; ++r)
      ivv[m][r] = invs[wm*128 + m*16 + (ln >> 4)*4 + r];

  char* eb = smem + wid * 16384;               // 64 rows(co) x 256B(pos), slot-XOR swizzled
  int y = y0 + wn;
  size_t obase = (size_t)n_img * COUT * (HH*WW) + (size_t)(y - 1) * WW;

  #pragma unroll
  for (int p = 0; p < 2; ++p) {
    #pragma unroll
    for (int m2 = 0; m2 < 4; ++m2) {
      int m = p*4 + m2;
      #pragma unroll
      for (int nn = 0; nn < 4; ++nn)
        #pragma unroll
        for (int r = 0; r < 4; ++r) {
          int row  = m2*16 + (ln >> 4)*4 + r;
          int slot = (nn*16 + (ln & 15) + 63) & 63;    // xx -> x=xx-1 (xx=0 parks at 63)
          int q    = (row >> 2) & 3;
          float v = fmaxf((float)acc[m][nn][r] * ivv[m][r], 0.0f);
          *(float*)(eb + row*256 + (((slot ^ (q << 4))) << 2)) = v;
        }
    }
    // read: 16-lane groups read 256B linear runs (conflict-free); store 224B global runs
    int c16 = ln & 15, rq = ln >> 4;
    #pragma unroll
    for (int j = 0; j < 16; ++j) {
      int row = j*4 + rq;
      int q   = (row >> 2) & 3;
      float4 v = *(const float4*)(eb + row*256 + ((c16 << 4) ^ (q << 6)));
      if (c16 < 14) {
        int co = wm*128 + p*64 + row;
        *(float4*)(out + obase + (size_t)co*(HH*WW) + c16*4) = v;
      }
    }
  }
}

extern "C" void kernel_launch(void* const* d_in, const int* in_sizes, int n_in,
                              void* d_out, int out_size, void* d_ws, size_t ws_size,
                              hipStream_t stream) {
  const float* x     = (const float*)d_in[0];
  const float* gamma = (const float*)d_in[1];
  const float* beta  = (const float*)d_in[2];
  const float* W     = (const float*)d_in[3];
  float* out = (float*)d_out;

  char* ws = (char*)d_ws;
  // layout: part [262144] | prm [8192] | invs [1024] | Wb i8 [589824] | pad | xb i8 @1MiB
  double*  part = (double*)ws;
  double*  prm  = (double*)(ws + 262144);
  float*   invs = (float*)(ws + 270336);
  int8_t*  Wb   = (int8_t*)(ws + 271360);
  int8_t*  xbuf = (int8_t*)(ws + 1048576);
  // xb: 64*58*64*256 = 60,817,408 B

  (void)hipFuncSetAttribute((const void*)conv_gemm,
                            hipFuncAttributeMaxDynamicSharedMemorySize, LDS_TOTAL);

  hipLaunchKernelGGL(wrepack,       dim3(256),    dim3(256), 0, stream, W, Wb, invs);
  hipLaunchKernelGGL(stats_partial, dim3(256*64), dim3(256), 0, stream, x, part);
  hipLaunchKernelGGL(stats_final,   dim3(1),      dim3(256), 0, stream, part, gamma, beta, prm);
  hipLaunchKernelGGL(binarize,      dim3(64*HP),  dim3(256), 0, stream, x, prm, xbuf);
  hipLaunchKernelGGL(conv_gemm,     dim3(896),    dim3(512), LDS_TOTAL, stream, xbuf, Wb, invs, out);
}